// Round 4
// baseline (151.129 us; speedup 1.0000x reference)
//
#include <hip/hip_runtime.h>
#include <hip/hip_bf16.h>

typedef _Float16 half2v __attribute__((ext_vector_type(2)));
typedef _Float16 half8 __attribute__((ext_vector_type(8)));
typedef __attribute__((ext_vector_type(4))) float floatx4;
typedef __attribute__((ext_vector_type(4))) unsigned int uintx4;

__device__ __forceinline__ half2v h2(float v) {
  return (half2v){(_Float16)v, (_Float16)v};
}

// tanh(x0),tanh(x1) -> packed-f16 Legendre P1..P8 for BOTH elements.
// fa0 = low halves (elem0), fa1 = high halves (elem1). ~42 VALU total.
__device__ __forceinline__ void legendre2_f16(float xv0, float xv1,
                                              half8* fa0, half8* fa1) {
  float e0 = __builtin_amdgcn_exp2f(xv0 * 2.885390081777927f); // 2*log2(e)
  float t0 = 1.0f - 2.0f * __builtin_amdgcn_rcpf(e0 + 1.0f);
  float e1 = __builtin_amdgcn_exp2f(xv1 * 2.885390081777927f);
  float t1 = 1.0f - 2.0f * __builtin_amdgcn_rcpf(e1 + 1.0f);
  half2v t;
  { auto tt = __builtin_amdgcn_cvt_pkrtz(t0, t1); __builtin_memcpy(&t, &tt, 4); }
  // P_k = u + c_k*(u - P_{k-2}), u = t*P_{k-1}, c_k=(k-1)/k   (packed, 3 ops/deg)
  half2v p1 = t;
  half2v u2 = t * p1, w2 = u2 - h2(1.0f);  half2v p2 = h2(0.5f)      * w2 + u2;
  half2v u3 = t * p2, w3 = u3 - p1;        half2v p3 = h2(2.0f/3.0f) * w3 + u3;
  half2v u4 = t * p3, w4 = u4 - p2;        half2v p4 = h2(0.75f)     * w4 + u4;
  half2v u5 = t * p4, w5 = u5 - p3;        half2v p5 = h2(0.8f)      * w5 + u5;
  half2v u6 = t * p5, w6 = u6 - p4;        half2v p6 = h2(5.0f/6.0f) * w6 + u6;
  half2v u7 = t * p6, w7 = u7 - p5;        half2v p7 = h2(6.0f/7.0f) * w7 + u7;
  half2v u8 = t * p7, w8 = u8 - p6;        half2v p8 = h2(7.0f/8.0f) * w8 + u8;
  unsigned P[8];
  __builtin_memcpy(&P[0], &p1, 4); __builtin_memcpy(&P[1], &p2, 4);
  __builtin_memcpy(&P[2], &p3, 4); __builtin_memcpy(&P[3], &p4, 4);
  __builtin_memcpy(&P[4], &p5, 4); __builtin_memcpy(&P[5], &p6, 4);
  __builtin_memcpy(&P[6], &p7, 4); __builtin_memcpy(&P[7], &p8, 4);
  union { unsigned u[4]; half8 h; } a0, a1;
#pragma unroll
  for (int j = 0; j < 4; ++j) {
    a0.u[j] = __builtin_amdgcn_perm(P[2*j+1], P[2*j], 0x05040100u); // low halves
    a1.u[j] = __builtin_amdgcn_perm(P[2*j+1], P[2*j], 0x07060302u); // high halves
  }
  *fa0 = a0.h;
  *fa1 = a1.h;
}

// ---- kernel 1: c_basis fp32 -> f16, transposed to ws[i][o][d] (256 KB) ----
__global__ void conv_kernel(const float* __restrict__ cb, _Float16* __restrict__ ws) {
  int t = blockIdx.x * 128 + threadIdx.x;   // 0..16383 = (o,i)
  int o = t >> 8;
  int i = t & 255;
  const floatx4* s = (const floatx4*)(cb + ((size_t)o * 256 + i) * 8);
  floatx4 v0 = s[0], v1 = s[1];
  union { _Float16 h[8]; uintx4 u; } w;
  w.h[0] = (_Float16)v0.x; w.h[1] = (_Float16)v0.y;
  w.h[2] = (_Float16)v0.z; w.h[3] = (_Float16)v0.w;
  w.h[4] = (_Float16)v1.x; w.h[5] = (_Float16)v1.y;
  w.h[6] = (_Float16)v1.z; w.h[7] = (_Float16)v1.w;
  *(uintx4*)(ws + (size_t)i * 512 + o * 8) = w.u;
}

// ---- kernel 2: LDS-free main loop, direct-register B ----
// 256 thr (4 waves = rh x kh), 64 rows/block, grid 1024 -> 4 blocks/CU
// = 16 waves/CU = 4 waves/SIMD. Wave (rh,kh): rows rb+rh*32..+31, K-half
// i in [kh*128, kh*128+128); i-map: i = kh*128 + q*32 + ch (q=lane>>4).
// B fragments are loaded straight from ws to VGPRs (identical bytes to the
// old LDS round-trip: ws + i*512 + nt*128 + m*8), pipelined 1 chunk ahead
// by the compiler (ordinary loads -> compiler waitcnts; no asm, no barriers,
// no LDS in the main loop). The two rh-waves of a kh read identical B
// addresses ~simultaneously -> per-CU L1 halves L2 B-traffic.
// x/y are zero-reuse streams: nontemporal so they don't evict ws from L2.
// Epilogue: kh=1 partials through 16 KB LDS scratch, kh=0 adds bias+stores.
__global__ __launch_bounds__(256, 4) void kan_kernel(
    const float* __restrict__ x, const _Float16* __restrict__ ws,
    const float* __restrict__ bias, float* __restrict__ y) {
  __shared__ __align__(16) float red[4096];   // 16 KB epilogue scratch

  const int tid  = threadIdx.x;
  const int wid  = tid >> 6;     // 0..3
  const int kh   = wid >> 1;     // K-half
  const int rh   = wid & 1;      // row-half
  const int lane = tid & 63;
  const int m    = lane & 15;
  const int q    = lane >> 4;
  const int rb   = blockIdx.x * 64;

  floatx4 acc[2][4];
#pragma unroll
  for (int a = 0; a < 2; ++a)
#pragma unroll
    for (int nt = 0; nt < 4; ++nt) acc[a][nt] = (floatx4){0.f, 0.f, 0.f, 0.f};

  // B fragment pointer: chunk ch, slot q -> i = kh*128 + q*32 + ch.
  // frag nt at +nt*128 halves; advances +512 halves (1 i-row) per chunk.
  const _Float16* bp = ws + (size_t)(kh * 128 + q * 32) * 512 + m * 8;

  // x: rows rb+rh*32+m (stream 0) and +16 (stream 1); cols kh*128+q*32+g*4.
  const float* xp0 = x + (size_t)(rb + rh * 32 + m) * 256 + kh * 128 + q * 32;
  const float* xp1 = xp0 + 16 * 256;

  // rolling 3-deep x window: slot g%3 holds group g (4 cols)
  floatx4 xs0[3], xs1[3];
  xs0[0] = __builtin_nontemporal_load((const floatx4*)(xp0));
  xs1[0] = __builtin_nontemporal_load((const floatx4*)(xp1));
  xs0[1] = __builtin_nontemporal_load((const floatx4*)(xp0 + 4));
  xs1[1] = __builtin_nontemporal_load((const floatx4*)(xp1 + 4));

  // prologue: B fragments for chunk 0
  half8 bc0 = *(const half8*)(bp + 0);
  half8 bc1 = *(const half8*)(bp + 128);
  half8 bc2 = *(const half8*)(bp + 256);
  half8 bc3 = *(const half8*)(bp + 384);
  bp += 512;

#define CHUNK(ch, DOX)                                                         \
  {                                                                            \
    half8 bn0, bn1, bn2, bn3;                                                  \
    if constexpr ((ch) < 31) {                                                 \
      bn0 = *(const half8*)(bp + 0);                                           \
      bn1 = *(const half8*)(bp + 128);                                         \
      bn2 = *(const half8*)(bp + 256);                                         \
      bn3 = *(const half8*)(bp + 384);                                         \
      bp += 512;                                                               \
    }                                                                          \
    if constexpr (DOX) {                                                       \
      constexpr int gp = (ch) / 4 + 2;                                         \
      xs0[gp % 3] = __builtin_nontemporal_load((const floatx4*)(xp0 + gp * 4));\
      xs1[gp % 3] = __builtin_nontemporal_load((const floatx4*)(xp1 + gp * 4));\
    }                                                                          \
    half8 f0, f1;                                                              \
    legendre2_f16(xs0[((ch) / 4) % 3][(ch) % 4],                               \
                  xs1[((ch) / 4) % 3][(ch) % 4], &f0, &f1);                    \
    __builtin_amdgcn_s_setprio(1);                                             \
    acc[0][0] = __builtin_amdgcn_mfma_f32_16x16x32_f16(f0, bc0, acc[0][0], 0, 0, 0); \
    acc[1][0] = __builtin_amdgcn_mfma_f32_16x16x32_f16(f1, bc0, acc[1][0], 0, 0, 0); \
    acc[0][1] = __builtin_amdgcn_mfma_f32_16x16x32_f16(f0, bc1, acc[0][1], 0, 0, 0); \
    acc[1][1] = __builtin_amdgcn_mfma_f32_16x16x32_f16(f1, bc1, acc[1][1], 0, 0, 0); \
    acc[0][2] = __builtin_amdgcn_mfma_f32_16x16x32_f16(f0, bc2, acc[0][2], 0, 0, 0); \
    acc[1][2] = __builtin_amdgcn_mfma_f32_16x16x32_f16(f1, bc2, acc[1][2], 0, 0, 0); \
    acc[0][3] = __builtin_amdgcn_mfma_f32_16x16x32_f16(f0, bc3, acc[0][3], 0, 0, 0); \
    acc[1][3] = __builtin_amdgcn_mfma_f32_16x16x32_f16(f1, bc3, acc[1][3], 0, 0, 0); \
    __builtin_amdgcn_s_setprio(0);                                             \
    if constexpr ((ch) < 31) { bc0 = bn0; bc1 = bn1; bc2 = bn2; bc3 = bn3; }   \
  }

  CHUNK(0, 1)  CHUNK(1, 0)  CHUNK(2, 0)  CHUNK(3, 0)
  CHUNK(4, 1)  CHUNK(5, 0)  CHUNK(6, 0)  CHUNK(7, 0)
  CHUNK(8, 1)  CHUNK(9, 0)  CHUNK(10, 0) CHUNK(11, 0)
  CHUNK(12, 1) CHUNK(13, 0) CHUNK(14, 0) CHUNK(15, 0)
  CHUNK(16, 1) CHUNK(17, 0) CHUNK(18, 0) CHUNK(19, 0)
  CHUNK(20, 1) CHUNK(21, 0) CHUNK(22, 0) CHUNK(23, 0)
  CHUNK(24, 0) CHUNK(25, 0) CHUNK(26, 0) CHUNK(27, 0)
  CHUNK(28, 0) CHUNK(29, 0) CHUNK(30, 0) CHUNK(31, 0)
#undef CHUNK

  // ---- epilogue: reduce the two K-partials through LDS, add bias, store ----
  __syncthreads();   // (harmless first sync; all mainloop state is registers)
  if (kh) {
#pragma unroll
    for (int a = 0; a < 2; ++a)
#pragma unroll
      for (int nt = 0; nt < 4; ++nt)
        *(floatx4*)(red + ((rh * 8 + a * 4 + nt) * 64 + lane) * 4) = acc[a][nt];
  }
  __syncthreads();
  if (!kh) {
    float bv[4];
#pragma unroll
    for (int nt = 0; nt < 4; ++nt) bv[nt] = bias[nt * 16 + m];
#pragma unroll
    for (int a = 0; a < 2; ++a) {
      int gr0 = rb + rh * 32 + a * 16 + q * 4;
#pragma unroll
      for (int nt = 0; nt < 4; ++nt) {
        floatx4 p = *(const floatx4*)(red + ((rh * 8 + a * 4 + nt) * 64 + lane) * 4);
#pragma unroll
        for (int r = 0; r < 4; ++r) {
          float v = acc[a][nt][r] + p[r] + bv[nt];
          __builtin_nontemporal_store(v, &y[(size_t)(gr0 + r) * 64 + nt * 16 + m]);
        }
      }
    }
  }
}

extern "C" void kernel_launch(void* const* d_in, const int* in_sizes, int n_in,
                              void* d_out, int out_size, void* d_ws, size_t ws_size,
                              hipStream_t stream) {
  const float* x    = (const float*)d_in[0];
  const float* cb   = (const float*)d_in[1];
  const float* bias = (const float*)d_in[2];
  float* y = (float*)d_out;
  _Float16* ws = (_Float16*)d_ws;
  int batch = in_sizes[0] / 256;  // 65536
  hipLaunchKernelGGL(conv_kernel, dim3(128), dim3(128), 0, stream, cb, ws);
  hipLaunchKernelGGL(kan_kernel, dim3(batch / 64), dim3(256), 0, stream, x, ws, bias, y);
}

// Round 5
// 118.691 us; speedup vs baseline: 1.2733x; 1.2733x over previous
//
#include <hip/hip_runtime.h>
#include <hip/hip_bf16.h>

typedef _Float16 half2v __attribute__((ext_vector_type(2)));
typedef _Float16 half8 __attribute__((ext_vector_type(8)));
typedef __attribute__((ext_vector_type(4))) float floatx4;
typedef __attribute__((ext_vector_type(4))) unsigned int uintx4;

#define GLOBAL_AS __attribute__((address_space(1)))
#define LDS_AS __attribute__((address_space(3)))

// async 16B/lane global->LDS DMA. LDS dest = WAVE-uniform base + lane*16.
__device__ __forceinline__ void async_ld16(const void* g, void* l) {
  __builtin_amdgcn_global_load_lds((const GLOBAL_AS unsigned int*)g,
                                   (LDS_AS unsigned int*)l, 16, 0, 0);
}

__device__ __forceinline__ half2v h2(float v) {
  return (half2v){(_Float16)v, (_Float16)v};
}

// tanh(x0),tanh(x1) -> packed-f16 Legendre P1..P8 for BOTH elements.
// fa0 = low halves (elem0), fa1 = high halves (elem1). ~42 VALU total.
__device__ __forceinline__ void legendre2_f16(float xv0, float xv1,
                                              half8* fa0, half8* fa1) {
  float e0 = __builtin_amdgcn_exp2f(xv0 * 2.885390081777927f); // 2*log2(e)
  float t0 = 1.0f - 2.0f * __builtin_amdgcn_rcpf(e0 + 1.0f);
  float e1 = __builtin_amdgcn_exp2f(xv1 * 2.885390081777927f);
  float t1 = 1.0f - 2.0f * __builtin_amdgcn_rcpf(e1 + 1.0f);
  half2v t;
  { auto tt = __builtin_amdgcn_cvt_pkrtz(t0, t1); __builtin_memcpy(&t, &tt, 4); }
  // P_k = u + c_k*(u - P_{k-2}), u = t*P_{k-1}, c_k=(k-1)/k   (packed, 3 ops/deg)
  half2v p1 = t;
  half2v u2 = t * p1, w2 = u2 - h2(1.0f);  half2v p2 = h2(0.5f)      * w2 + u2;
  half2v u3 = t * p2, w3 = u3 - p1;        half2v p3 = h2(2.0f/3.0f) * w3 + u3;
  half2v u4 = t * p3, w4 = u4 - p2;        half2v p4 = h2(0.75f)     * w4 + u4;
  half2v u5 = t * p4, w5 = u5 - p3;        half2v p5 = h2(0.8f)      * w5 + u5;
  half2v u6 = t * p5, w6 = u6 - p4;        half2v p6 = h2(5.0f/6.0f) * w6 + u6;
  half2v u7 = t * p6, w7 = u7 - p5;        half2v p7 = h2(6.0f/7.0f) * w7 + u7;
  half2v u8 = t * p7, w8 = u8 - p6;        half2v p8 = h2(7.0f/8.0f) * w8 + u8;
  unsigned P[8];
  __builtin_memcpy(&P[0], &p1, 4); __builtin_memcpy(&P[1], &p2, 4);
  __builtin_memcpy(&P[2], &p3, 4); __builtin_memcpy(&P[3], &p4, 4);
  __builtin_memcpy(&P[4], &p5, 4); __builtin_memcpy(&P[5], &p6, 4);
  __builtin_memcpy(&P[6], &p7, 4); __builtin_memcpy(&P[7], &p8, 4);
  union { unsigned u[4]; half8 h; } a0, a1;
#pragma unroll
  for (int j = 0; j < 4; ++j) {
    a0.u[j] = __builtin_amdgcn_perm(P[2*j+1], P[2*j], 0x05040100u); // low halves
    a1.u[j] = __builtin_amdgcn_perm(P[2*j+1], P[2*j], 0x07060302u); // high halves
  }
  *fa0 = a0.h;
  *fa1 = a1.h;
}

// ---- kernel 1: c_basis fp32 -> f16, transposed to ws[i][o][d] (256 KB) ----
__global__ void conv_kernel(const float* __restrict__ cb, _Float16* __restrict__ ws) {
  int t = blockIdx.x * 128 + threadIdx.x;   // 0..16383 = (o,i)
  int o = t >> 8;
  int i = t & 255;
  const floatx4* s = (const floatx4*)(cb + ((size_t)o * 256 + i) * 8);
  floatx4 v0 = s[0], v1 = s[1];
  union { _Float16 h[8]; uintx4 u; } w;
  w.h[0] = (_Float16)v0.x; w.h[1] = (_Float16)v0.y;
  w.h[2] = (_Float16)v0.z; w.h[3] = (_Float16)v0.w;
  w.h[4] = (_Float16)v1.x; w.h[5] = (_Float16)v1.y;
  w.h[6] = (_Float16)v1.z; w.h[7] = (_Float16)v1.w;
  *(uintx4*)(ws + (size_t)i * 512 + o * 8) = w.u;
}

// ---- kernel 2: R0 skeleton + in-block K-split -> 4 waves/SIMD ----
// 256 thr = 4 waves (kh = wid>>1 K-half, rh = wid&1 row-half), 64 rows/block,
// grid 1024, LDS 40 KB -> 4 blocks/CU = 16 waves/CU = 4 waves/SIMD.
// 16 steps; step stages 16 B i-rows (i = kh*128 + step*8 + 0..7 per panel;
// DMA slot t=wid*4+j -> i = (t>>3)*128 + step*8 + (t&7)) + 4 KB of x
// (64 rows x 16 cols = the two 8-col panels), all consumed next step.
// Verified R0 discipline: WAR barrier -> stage(step+1) [5 DMA/wave] ->
// vmcnt(5) [drains step's DMAs; exact: no other VMEM in loop] -> RAW barrier.
// x LDS: 16B units, unit(row,p) stored at p' = p ^ ((row>>1)&3) (both-sides
// XOR swizzle; read lands 2-way bank aliasing = free). Wave (kh,rh) reads
// x[rh*32+m(+16)][kh*2+ks panel, elem q] and B rows kh*8+ks*4+q (R0-verified
// fragment mapping q*512+m*8, +nt*128). Epilogue: kh-reduction via LDS.
#define NSTEP 16

__global__ __launch_bounds__(256, 4) void kan_kernel(
    const float* __restrict__ x, const _Float16* __restrict__ ws,
    const float* __restrict__ bias, float* __restrict__ y) {
  __shared__ __align__(16) _Float16 bt[2][8192]; // 16 i-rows x 512, dbuf: 32 KB
  __shared__ __align__(16) float xs[2][1024];    // 64 rows x 16 cols, dbuf: 8 KB

  const int tid  = threadIdx.x;
  const int wid  = tid >> 6;     // 0..3
  const int kh   = wid >> 1;     // K-half
  const int rh   = wid & 1;      // row-half
  const int lane = tid & 63;
  const int m    = lane & 15;
  const int q    = lane >> 4;
  const int rb   = blockIdx.x * 64;

  floatx4 acc[2][4];
#pragma unroll
  for (int a = 0; a < 2; ++a)
#pragma unroll
    for (int nt = 0; nt < 4; ++nt) acc[a][nt] = (floatx4){0.f, 0.f, 0.f, 0.f};

  // B DMA src: 4 slots t = wid*4 + j; i-row i = (t>>3)*128 + step*8 + (t&7)
  const _Float16* bsrc[4];
#pragma unroll
  for (int j = 0; j < 4; ++j) {
    int t = wid * 4 + j;
    bsrc[j] = ws + (size_t)((t >> 3) * 128 + (t & 7)) * 512 + lane * 8;
  }

  // x DMA src: unit u = wid*64 + lane; row = u>>2, stored piece p' = u&3,
  // actual piece p = p' ^ ((row>>1)&3); col = (p>>1)*128 + (p&1)*4 + step*8
  const float* xsrc;
  {
    int u = wid * 64 + lane;
    int row = u >> 2;
    int p = (u & 3) ^ ((row >> 1) & 3);
    xsrc = x + (size_t)(rb + row) * 256 + (p >> 1) * 128 + (p & 1) * 4;
  }

  // 5 DMAs per wave per step: 4 B i-rows (1 KB each) + 1 x slot (1 KB)
  auto stage = [&](int b) {
#pragma unroll
    for (int j = 0; j < 4; ++j) {
      async_ld16(bsrc[j], &bt[b][(wid * 4 + j) * 512]);
      bsrc[j] += 8 * 512;
    }
    async_ld16(xsrc, &xs[b][wid * 256]);
    xsrc += 8;
  };

  stage(0);

  const int row0 = rh * 32 + m;          // row-stream 0 (stream 1 = +16)
  const int sw   = (row0 >> 1) & 3;      // x swizzle key (same for row0+16)

#pragma unroll 2
  for (int ch = 0; ch < NSTEP; ++ch) {
    const int buf = ch & 1;
    // WAR: all 4 waves done computing step ch-1 (which read buf^1)
    asm volatile("s_barrier" ::: "memory");
    if (ch + 1 < NSTEP) {
      stage(buf ^ 1);
      asm volatile("s_waitcnt vmcnt(5)" ::: "memory"); // own step-ch DMAs landed
    } else {
      asm volatile("s_waitcnt vmcnt(0)" ::: "memory");
    }
    // RAW: ALL waves' step-ch slices landed
    asm volatile("s_barrier" ::: "memory");

#pragma unroll
    for (int ks = 0; ks < 2; ++ks) {
      const int xi = row0 * 16 + (((kh * 2 + ks) ^ sw) << 2) + q;
      float xv0 = xs[buf][xi];
      float xv1 = xs[buf][xi + 256];     // row0+16 -> +16*16 floats
      half8 f0, f1;
      legendre2_f16(xv0, xv1, &f0, &f1);
      const _Float16* bp = &bt[buf][(kh * 8 + ks * 4 + q) * 512 + m * 8];
      half8 fb0 = *(const half8*)(bp + 0);
      half8 fb1 = *(const half8*)(bp + 128);
      half8 fb2 = *(const half8*)(bp + 256);
      half8 fb3 = *(const half8*)(bp + 384);
      __builtin_amdgcn_s_setprio(1);
      acc[0][0] = __builtin_amdgcn_mfma_f32_16x16x32_f16(f0, fb0, acc[0][0], 0, 0, 0);
      acc[1][0] = __builtin_amdgcn_mfma_f32_16x16x32_f16(f1, fb0, acc[1][0], 0, 0, 0);
      acc[0][1] = __builtin_amdgcn_mfma_f32_16x16x32_f16(f0, fb1, acc[0][1], 0, 0, 0);
      acc[1][1] = __builtin_amdgcn_mfma_f32_16x16x32_f16(f1, fb1, acc[1][1], 0, 0, 0);
      acc[0][2] = __builtin_amdgcn_mfma_f32_16x16x32_f16(f0, fb2, acc[0][2], 0, 0, 0);
      acc[1][2] = __builtin_amdgcn_mfma_f32_16x16x32_f16(f1, fb2, acc[1][2], 0, 0, 0);
      acc[0][3] = __builtin_amdgcn_mfma_f32_16x16x32_f16(f0, fb3, acc[0][3], 0, 0, 0);
      acc[1][3] = __builtin_amdgcn_mfma_f32_16x16x32_f16(f1, fb3, acc[1][3], 0, 0, 0);
      __builtin_amdgcn_s_setprio(0);
    }
  }

  // ---- epilogue: reduce the two K-partials through LDS, add bias, store ----
  float* red = (float*)&bt[0][0];        // 16 KB scratch, reuse staging LDS
  __syncthreads();                       // all waves past vmcnt(0) + compute
  if (kh) {
#pragma unroll
    for (int a = 0; a < 2; ++a)
#pragma unroll
      for (int nt = 0; nt < 4; ++nt)
        *(floatx4*)(red + ((rh * 8 + a * 4 + nt) * 64 + lane) * 4) = acc[a][nt];
  }
  __syncthreads();
  if (!kh) {
    float bv[4];
#pragma unroll
    for (int nt = 0; nt < 4; ++nt) bv[nt] = bias[nt * 16 + m];
#pragma unroll
    for (int a = 0; a < 2; ++a) {
      int gr0 = rb + rh * 32 + a * 16 + q * 4;
#pragma unroll
      for (int nt = 0; nt < 4; ++nt) {
        floatx4 p = *(const floatx4*)(red + ((rh * 8 + a * 4 + nt) * 64 + lane) * 4);
#pragma unroll
        for (int r = 0; r < 4; ++r) {
          y[(size_t)(gr0 + r) * 64 + nt * 16 + m] = acc[a][nt][r] + p[r] + bv[nt];
        }
      }
    }
  }
}

extern "C" void kernel_launch(void* const* d_in, const int* in_sizes, int n_in,
                              void* d_out, int out_size, void* d_ws, size_t ws_size,
                              hipStream_t stream) {
  const float* x    = (const float*)d_in[0];
  const float* cb   = (const float*)d_in[1];
  const float* bias = (const float*)d_in[2];
  float* y = (float*)d_out;
  _Float16* ws = (_Float16*)d_ws;
  int batch = in_sizes[0] / 256;  // 65536
  hipLaunchKernelGGL(conv_kernel, dim3(128), dim3(128), 0, stream, cb, ws);
  hipLaunchKernelGGL(kan_kernel, dim3(batch / 64), dim3(256), 0, stream, x, ws, bias, y);
}